// Round 1
// baseline (32.774 us; speedup 1.0000x reference)
//
#include <hip/hip_runtime.h>

// WeightedStateLoss4: B=512, H=2048, D=64, fp32.
// t[i]   = count_nonzero(targ[i, :, 1])
// w[i]   = 1 + 0.7 * (t/(H-1))^2.5
// idx[i] = clamp(t-1, 0, H-1)        (JAX take_along_axis clips OOB)
// out    = mean_i( (pred[i,idx,0]-targ[i,idx,0])^2 * w[i] * D )

#define BB 512
#define HH 2048
#define DD 64

__global__ __launch_bounds__(256) void WeightedStateLoss4_kernel(
    const float* __restrict__ pred,
    const float* __restrict__ targ,
    float* __restrict__ out)
{
    const int i   = blockIdx.x;      // sample
    const int tid = threadIdx.x;     // 0..255

    const float* trow = targ + (size_t)i * HH * DD;

    // Each thread scans 8 strided elements of channel 1. Issue all loads
    // independently (unrolled) so they overlap.
    int cnt = 0;
    float v[HH / 256];
#pragma unroll
    for (int k = 0; k < HH / 256; ++k) {
        const int h = tid + k * 256;
        v[k] = trow[(size_t)h * DD + 1];
    }
#pragma unroll
    for (int k = 0; k < HH / 256; ++k) {
        cnt += (v[k] != 0.0f) ? 1 : 0;
    }

    // Wave-64 shuffle reduction.
#pragma unroll
    for (int off = 32; off > 0; off >>= 1)
        cnt += __shfl_down(cnt, off, 64);

    __shared__ int s[4];
    const int wave = tid >> 6;
    const int lane = tid & 63;
    if (lane == 0) s[wave] = cnt;
    __syncthreads();

    if (tid == 0) {
        const int t = s[0] + s[1] + s[2] + s[3];
        const float tf = (float)t;
        const float ratio = tf / (float)(HH - 1);
        const float w = 1.0f + 0.7f * powf(ratio, 2.5f);

        int idx = t - 1;
        idx = idx < 0 ? 0 : (idx > HH - 1 ? HH - 1 : idx);

        const size_t base = ((size_t)i * HH + (size_t)idx) * DD;  // channel 0
        const float p = pred[base];
        const float q = targ[base];
        const float d = p - q;
        const float val = d * d * w * (float)DD * (1.0f / (float)BB);
        atomicAdd(out, val);
    }
}

extern "C" void kernel_launch(void* const* d_in, const int* in_sizes, int n_in,
                              void* d_out, int out_size, void* d_ws, size_t ws_size,
                              hipStream_t stream)
{
    const float* pred = (const float*)d_in[0];
    const float* targ = (const float*)d_in[1];
    float* out = (float*)d_out;

    // Output is accumulated via atomicAdd -> must start at zero every call
    // (harness poisons once, never re-poisons between graph replays).
    hipMemsetAsync(out, 0, sizeof(float) * (size_t)out_size, stream);

    WeightedStateLoss4_kernel<<<BB, 256, 0, stream>>>(pred, targ, out);
}

// Round 2
// 29.664 us; speedup vs baseline: 1.1048x; 1.1048x over previous
//
#include <hip/hip_runtime.h>

// WeightedStateLoss4: B=512, H=2048, D=64, fp32.
// t[i]   = count_nonzero(targ[i, :, 1])
// w[i]   = 1 + 0.7 * (t/(H-1))^2.5
// idx[i] = clamp(t-1, 0, H-1)        (JAX take_along_axis clips OOB)
// out    = mean_i( (pred[i,idx,0]-targ[i,idx,0])^2 * w[i] * D )

#define BB 512
#define HH 2048
#define DD 64
#define CHUNKS 4            // blocks per sample
#define HPC (HH / CHUNKS)   // 512 h-values per chunk; 256 threads -> 2 each

// Kernel A: per-(sample,chunk) nonzero count of targ[:, :, 1].
// grid = (CHUNKS, BB). Each block writes ONE int to its own ws slot
// (fully overwritten every call -> no zero-init, no atomics).
__global__ __launch_bounds__(256) void wsl4_count(
    const float* __restrict__ targ, int* __restrict__ partial)
{
    const int c   = blockIdx.x;
    const int i   = blockIdx.y;
    const int tid = threadIdx.x;

    const float* p = targ + (size_t)i * HH * DD + (size_t)c * HPC * DD + 1;

    // two independent strided loads per thread (overlapped)
    const float a = p[(size_t)tid * DD];
    const float b = p[((size_t)tid + 256) * DD];
    int cnt = (a != 0.0f ? 1 : 0) + (b != 0.0f ? 1 : 0);

#pragma unroll
    for (int off = 32; off > 0; off >>= 1)
        cnt += __shfl_down(cnt, off, 64);

    __shared__ int s[4];
    if ((tid & 63) == 0) s[tid >> 6] = cnt;
    __syncthreads();

    if (tid == 0) partial[i * CHUNKS + c] = s[0] + s[1] + s[2] + s[3];
}

// Kernel B: one block, 512 threads (= one sample each).
// Sum partials, weight, clamped gather, block-reduce, single store.
__global__ __launch_bounds__(512) void wsl4_final(
    const float* __restrict__ pred, const float* __restrict__ targ,
    const int* __restrict__ partial, float* __restrict__ out)
{
    const int i = threadIdx.x;   // sample 0..511

    const int4 t4 = *(const int4*)(partial + i * CHUNKS);
    const int t = t4.x + t4.y + t4.z + t4.w;

    const float ratio = (float)t / (float)(HH - 1);
    const float w = 1.0f + 0.7f * powf(ratio, 2.5f);

    int idx = t - 1;
    idx = idx < 0 ? 0 : (idx > HH - 1 ? HH - 1 : idx);

    const size_t base = ((size_t)i * HH + (size_t)idx) * DD;  // channel 0
    const float d = pred[base] - targ[base];
    float val = d * d * w * ((float)DD / (float)BB);

#pragma unroll
    for (int off = 32; off > 0; off >>= 1)
        val += __shfl_down(val, off, 64);

    __shared__ float sf[8];
    if ((i & 63) == 0) sf[i >> 6] = val;
    __syncthreads();

    if (i == 0) {
        float tot = 0.0f;
#pragma unroll
        for (int k = 0; k < 8; ++k) tot += sf[k];
        out[0] = tot;
    }
}

extern "C" void kernel_launch(void* const* d_in, const int* in_sizes, int n_in,
                              void* d_out, int out_size, void* d_ws, size_t ws_size,
                              hipStream_t stream)
{
    const float* pred = (const float*)d_in[0];
    const float* targ = (const float*)d_in[1];
    float* out = (float*)d_out;
    int* partial = (int*)d_ws;   // BB*CHUNKS ints = 8 KB

    dim3 grid(CHUNKS, BB);
    wsl4_count<<<grid, 256, 0, stream>>>(targ, partial);
    wsl4_final<<<1, 512, 0, stream>>>(pred, targ, partial, out);
}